// Round 9
// baseline (1412.857 us; speedup 1.0000x reference)
//
#include <hip/hip_runtime.h>
#include <hip/hip_bf16.h>
#include <stdint.h>

#define NUM_IN  2048   // K
#define NUM_OUT 8192   // N
#define BATCH   4096   // M
#define SD      5

#define BM 256
#define BN 256
#define BK 32
#define NT (NUM_IN / BK)      // 64 K-tiles
#define TILEE (BM * BK)       // 8192 elements per operand per K-tile

typedef __bf16 bf16x8 __attribute__((ext_vector_type(8)));
typedef float  f32x4  __attribute__((ext_vector_type(4)));
typedef unsigned short ushort_t;
typedef ushort_t ushort8 __attribute__((ext_vector_type(8)));

static __device__ __forceinline__ ushort_t bf16_bits(float f) {
  __hip_bfloat16 h = __float2bfloat16(f);
  ushort_t u;
  __builtin_memcpy(&u, &h, 2);
  return u;
}

// ---------- inputs f32 -> bf16 (vectorized) ----------
__global__ __launch_bounds__(256) void cvt_kernel(const float* __restrict__ x,
                                                  ushort_t* __restrict__ y) {
  const int i = (blockIdx.x * 256 + threadIdx.x) * 8;
  float4 v0 = *reinterpret_cast<const float4*>(x + i);
  float4 v1 = *reinterpret_cast<const float4*>(x + i + 4);
  ushort8 o;
  o[0] = bf16_bits(v0.x); o[1] = bf16_bits(v0.y);
  o[2] = bf16_bits(v0.z); o[3] = bf16_bits(v0.w);
  o[4] = bf16_bits(v1.x); o[5] = bf16_bits(v1.y);
  o[6] = bf16_bits(v1.z); o[7] = bf16_bits(v1.w);
  *reinterpret_cast<ushort8*>(y + i) = o;
}

// ---------- W^T generation: in_pos/init_in staged in LDS ----------
__global__ __launch_bounds__(256) void genw_kernel(
    const float* __restrict__ in_pos, const float* __restrict__ out_pos,
    const float* __restrict__ init_in, const float* __restrict__ init_out,
    ushort_t* __restrict__ Wt) {
  __shared__ float s_ip[NUM_IN * SD];    // 40 KB
  __shared__ float s_iip[NUM_IN * SD];   // 40 KB
  const int tid = threadIdx.x;
#pragma unroll
  for (int i = 0; i < 10; ++i) {
    const int idx = i * 1024 + tid * 4;
    *reinterpret_cast<float4*>(&s_ip[idx]) =
        *reinterpret_cast<const float4*>(in_pos + idx);
    *reinterpret_cast<float4*>(&s_iip[idx]) =
        *reinterpret_cast<const float4*>(init_in + idx);
  }
  __syncthreads();

  const int n  = blockIdx.x * 16 + (tid >> 4);
  const int kg = tid & 15;
  float op[SD], iop[SD];
#pragma unroll
  for (int d = 0; d < SD; ++d) {
    op[d]  = out_pos[n * SD + d];
    iop[d] = init_out[n * SD + d];
  }
#pragma unroll 1
  for (int kb = 0; kb < 16; ++kb) {
    const int k0 = kb * 128 + kg * 8;
    float buf[40], ibuf[40];
#pragma unroll
    for (int j = 0; j < 10; ++j) {
      float4 v = *reinterpret_cast<const float4*>(&s_ip[k0 * SD + j * 4]);
      buf[4 * j + 0] = v.x; buf[4 * j + 1] = v.y;
      buf[4 * j + 2] = v.z; buf[4 * j + 3] = v.w;
      float4 u = *reinterpret_cast<const float4*>(&s_iip[k0 * SD + j * 4]);
      ibuf[4 * j + 0] = u.x; ibuf[4 * j + 1] = u.y;
      ibuf[4 * j + 2] = u.z; ibuf[4 * j + 3] = u.w;
    }
    ushort8 o;
#pragma unroll
    for (int i = 0; i < 8; ++i) {
      float d1 = 0.f, d0 = 0.f;
#pragma unroll
      for (int d = 0; d < SD; ++d) {
        float a = buf[i * SD + d] - op[d];
        float b = ibuf[i * SD + d] - iop[d];
        d1 += a * a;
        d0 += b * b;
      }
      o[i] = bf16_bits(sqrtf(d1) - sqrtf(d0));
    }
    *reinterpret_cast<ushort8*>(Wt + (size_t)n * NUM_IN + k0) = o;
  }
}

// ---------- GEMM: BK=32 dbuf (64 KB LDS -> 2 blocks/CU), lookahead KTILE ----
// 512 blocks = 256 CU x 2 -> all co-resident, 4 waves/SIMD; cross-block
// anti-phase overlap fills barrier/drain bubbles. Layout/swizzle = round-8
// verified zero-conflict: row-paired 128B lines, line L = row>>1,
// logical chunk c = 4*(row&1)+ck stored at c ^ (L&7).
__global__ __launch_bounds__(512, 4) void gemm_kernel(
    const ushort_t* __restrict__ A,    // [M][K] bf16
    const ushort_t* __restrict__ Bt,   // [N][K] bf16
    const float* __restrict__ bias,    // [N]
    float* __restrict__ C) {           // [M][N] f32
  __shared__ __align__(16) ushort_t sA[2 * TILEE];   // 32 KiB
  __shared__ __align__(16) ushort_t sB[2 * TILEE];   // 32 KiB

  const int tid  = threadIdx.x;
  const int w    = tid >> 6;         // 0..7
  const int l    = tid & 63;
  const int wm   = w >> 2;           // 0..1
  const int wn   = w & 3;            // 0..3
  const int lrow = l & 15;
  const int lkc  = l >> 4;           // 0..3

  // bijective XCD swizzle (512 = 8*64)
  const int orig = blockIdx.x;
  const int lin  = (orig & 7) * 64 + (orig >> 3);
  const int bx   = lin >> 4;         // 0..31 N-block
  const int by   = lin & 15;         // 0..15 M-block
  const int m0   = by * BM;
  const int n0   = bx * BN;

  // ---- fragment lane offset (elements) ----
  // phys slot = (4*(lrow&1) + lkc) ^ (lrow>>1); addr = line*64 + phys*8
  const int phys  = ((4 * (lrow & 1) + lkc) ^ (lrow >> 1));
  const int laneo = (lrow >> 1) * 64 + phys * 8;
  const int AbW = wm * 4096;   // + mh*2048 + mi*512
  const int BbW = wn * 2048;   // + nh*1024 + nj*512

  // ---- staging geometry (round-8 verified) ----
  const int cc  = (tid & 7) ^ ((tid >> 3) & 7);
  const int row = 2 * (tid >> 3) + (cc >> 2);
  const int ke  = (cc & 3) * 8;
  const ushort_t* pA0 = A  + (size_t)(m0 + row) * NUM_IN + ke;
  const ushort_t* pA1 = A  + (size_t)(m0 + row + 128) * NUM_IN + ke;
  const ushort_t* pB0 = Bt + (size_t)(n0 + row) * NUM_IN + ke;
  const ushort_t* pB1 = Bt + (size_t)(n0 + row + 128) * NUM_IN + ke;

#define GLDS(src, dst)                                                         \
  __builtin_amdgcn_global_load_lds(                                            \
      reinterpret_cast<const __attribute__((address_space(1))) uint32_t*>(     \
          (uintptr_t)(src)),                                                   \
      reinterpret_cast<__attribute__((address_space(3))) uint32_t*>(           \
          (uintptr_t)(dst)),                                                   \
      16, 0, 0)

// one K-tile stage = 4 gloads/thread (A:2, B:2)
#define STAGE(bs, kt)                                                          \
  {                                                                            \
    GLDS(pA0 + (kt), &sA[(bs) * TILEE + tid * 8]);                             \
    GLDS(pA1 + (kt), &sA[(bs) * TILEE + tid * 8 + 4096]);                      \
    GLDS(pB0 + (kt), &sB[(bs) * TILEE + tid * 8]);                             \
    GLDS(pB1 + (kt), &sB[(bs) * TILEE + tid * 8 + 4096]);                      \
  }

#define RD_A(arr, bs, mh)                                                      \
  {                                                                            \
    _Pragma("unroll")                                                          \
    for (int mi = 0; mi < 4; ++mi)                                             \
      arr[mi] = *reinterpret_cast<const bf16x8*>(                              \
          &sA[(bs) * TILEE + AbW + (mh) * 2048 + mi * 512 + laneo]);           \
  }
#define RD_B(arr, bs, nh)                                                      \
  {                                                                            \
    _Pragma("unroll")                                                          \
    for (int nj = 0; nj < 2; ++nj)                                             \
      arr[nj] = *reinterpret_cast<const bf16x8*>(                              \
          &sB[(bs) * TILEE + BbW + (nh) * 1024 + nj * 512 + laneo]);           \
  }

#define MFMA8(mh, nh, Aa, Bx)                                                  \
  {                                                                            \
    __builtin_amdgcn_s_setprio(1);                                             \
    _Pragma("unroll")                                                          \
    for (int mi = 0; mi < 4; ++mi)                                             \
      _Pragma("unroll")                                                        \
      for (int nj = 0; nj < 2; ++nj)                                           \
        acc[(mh) * 4 + mi][(nh) * 2 + nj] =                                    \
            __builtin_amdgcn_mfma_f32_16x16x32_bf16(                           \
                Aa[mi], Bx[nj], acc[(mh) * 4 + mi][(nh) * 2 + nj], 0, 0, 0);   \
    __builtin_amdgcn_s_setprio(0);                                             \
  }

#define LGKM(n)  asm volatile("s_waitcnt lgkmcnt(" #n ")" ::: "memory")
#define SCHED0   __builtin_amdgcn_sched_barrier(0)
#define BARRIER  __builtin_amdgcn_s_barrier()
#define VMCNT0   asm volatile("s_waitcnt vmcnt(0)" ::: "memory")

// One K-tile: read buf CUR, stage tile(ktn) -> buf NXT.
// vmcnt(0) at tile end drains this tile's 4 stage-loads, issued ~a full
// tile earlier. Read lookahead via counted lgkmcnt (round-7 pattern).
#define KTILE(CUR, NXT, ktn)                                                   \
  {                                                                            \
    STAGE(NXT, ktn)                                                            \
    RD_A(aE, CUR, 0) RD_B(b0, CUR, 0)                                          \
    RD_B(b1, CUR, 1)                                                           \
    LGKM(2); SCHED0;                                                           \
    MFMA8(0, 0, aE, b0)                                                        \
    RD_A(aO, CUR, 1)                                                           \
    LGKM(4); SCHED0;                                                           \
    MFMA8(0, 1, aE, b1)                                                        \
    LGKM(0); SCHED0;                                                           \
    MFMA8(1, 0, aO, b0)                                                        \
    MFMA8(1, 1, aO, b1)                                                        \
    VMCNT0;                                                                    \
    BARRIER;                                                                   \
  }

  f32x4 acc[8][4];
#pragma unroll
  for (int i = 0; i < 8; ++i)
#pragma unroll
    for (int j = 0; j < 4; ++j) acc[i][j] = f32x4{0.f, 0.f, 0.f, 0.f};

  bf16x8 aE[4], aO[4], b0[2], b1[2];

  // prologue: stage tile 0 into buf0
  STAGE(0, 0)
  VMCNT0;
  BARRIER;

#pragma unroll 1
  for (int tt = 0; tt < NT; tt += 2) {
    const int k1 = (tt + 1 < NT ? tt + 1 : NT - 1) * BK;
    const int k2 = (tt + 2 < NT ? tt + 2 : NT - 1) * BK;
    KTILE(0, 1, k1)
    KTILE(1, 0, k2)
  }

  // ---- epilogue: C = acc + bias ----
  const int er = l >> 4;          // 0..3
  const int ec = l & 15;
#pragma unroll
  for (int nh = 0; nh < 2; ++nh) {
#pragma unroll
    for (int nj = 0; nj < 2; ++nj) {
      const int col = n0 + wn * 64 + nh * 32 + nj * 16 + ec;
      const float bi = bias[col];
#pragma unroll
      for (int mh = 0; mh < 2; ++mh) {
#pragma unroll
        for (int mi = 0; mi < 4; ++mi) {
#pragma unroll
          for (int j = 0; j < 4; ++j) {
            const int row = m0 + wm * 128 + mh * 64 + mi * 16 + er * 4 + j;
            C[(size_t)row * NUM_OUT + col] =
                acc[mh * 4 + mi][nh * 2 + nj][j] + bi;
          }
        }
      }
    }
  }
#undef KTILE
#undef STAGE
#undef RD_A
#undef RD_B
#undef MFMA8
#undef GLDS
}

extern "C" void kernel_launch(void* const* d_in, const int* in_sizes, int n_in,
                              void* d_out, int out_size, void* d_ws, size_t ws_size,
                              hipStream_t stream) {
  const float* inputs   = (const float*)d_in[0];  // [4096,2048]
  const float* init_in  = (const float*)d_in[1];  // [2048,1,5]
  const float* init_out = (const float*)d_in[2];  // [1,8192,5]
  const float* in_pos   = (const float*)d_in[3];  // [2048,1,5]
  const float* out_pos  = (const float*)d_in[4];  // [1,8192,5]
  const float* biases   = (const float*)d_in[5];  // [8192]
  float* out = (float*)d_out;                     // [4096,8192]

  ushort_t* Abf = (ushort_t*)d_ws;
  ushort_t* Wt  = (ushort_t*)((char*)d_ws + (size_t)BATCH * NUM_IN * 2);

  cvt_kernel<<<(BATCH * NUM_IN) / (256 * 8), 256, 0, stream>>>(inputs, Abf);
  genw_kernel<<<NUM_OUT / 16, 256, 0, stream>>>(
      in_pos, out_pos, init_in, init_out, Wt);
  gemm_kernel<<<(BATCH / BM) * (NUM_OUT / BN), 512, 0, stream>>>(
      Abf, Wt, biases, out);
}

// Round 10
// 174.993 us; speedup vs baseline: 8.0738x; 8.0738x over previous
//
#include <hip/hip_runtime.h>
#include <hip/hip_bf16.h>
#include <stdint.h>

#define NUM_IN  2048   // K
#define NUM_OUT 8192   // N
#define BATCH   4096   // M
#define SD      5

#define BM 256
#define BN 256
#define BK 32
#define NT (NUM_IN / BK)      // 64 K-tiles
#define TILEE (BM * BK)       // 8192 elements per operand per K-tile

typedef __bf16 bf16x8 __attribute__((ext_vector_type(8)));
typedef float  f32x4  __attribute__((ext_vector_type(4)));
typedef unsigned short ushort_t;
typedef ushort_t ushort8 __attribute__((ext_vector_type(8)));

static __device__ __forceinline__ ushort_t bf16_bits(float f) {
  __hip_bfloat16 h = __float2bfloat16(f);
  ushort_t u;
  __builtin_memcpy(&u, &h, 2);
  return u;
}

// ---------- inputs f32 -> bf16 (vectorized) ----------
__global__ __launch_bounds__(256) void cvt_kernel(const float* __restrict__ x,
                                                  ushort_t* __restrict__ y) {
  const int i = (blockIdx.x * 256 + threadIdx.x) * 8;
  float4 v0 = *reinterpret_cast<const float4*>(x + i);
  float4 v1 = *reinterpret_cast<const float4*>(x + i + 4);
  ushort8 o;
  o[0] = bf16_bits(v0.x); o[1] = bf16_bits(v0.y);
  o[2] = bf16_bits(v0.z); o[3] = bf16_bits(v0.w);
  o[4] = bf16_bits(v1.x); o[5] = bf16_bits(v1.y);
  o[6] = bf16_bits(v1.z); o[7] = bf16_bits(v1.w);
  *reinterpret_cast<ushort8*>(y + i) = o;
}

// ---------- W^T generation: in_pos/init_in staged in LDS ----------
__global__ __launch_bounds__(256) void genw_kernel(
    const float* __restrict__ in_pos, const float* __restrict__ out_pos,
    const float* __restrict__ init_in, const float* __restrict__ init_out,
    ushort_t* __restrict__ Wt) {
  __shared__ float s_ip[NUM_IN * SD];    // 40 KB
  __shared__ float s_iip[NUM_IN * SD];   // 40 KB
  const int tid = threadIdx.x;
#pragma unroll
  for (int i = 0; i < 10; ++i) {
    const int idx = i * 1024 + tid * 4;
    *reinterpret_cast<float4*>(&s_ip[idx]) =
        *reinterpret_cast<const float4*>(in_pos + idx);
    *reinterpret_cast<float4*>(&s_iip[idx]) =
        *reinterpret_cast<const float4*>(init_in + idx);
  }
  __syncthreads();

  const int n  = blockIdx.x * 16 + (tid >> 4);
  const int kg = tid & 15;
  float op[SD], iop[SD];
#pragma unroll
  for (int d = 0; d < SD; ++d) {
    op[d]  = out_pos[n * SD + d];
    iop[d] = init_out[n * SD + d];
  }
#pragma unroll 1
  for (int kb = 0; kb < 16; ++kb) {
    const int k0 = kb * 128 + kg * 8;
    float buf[40], ibuf[40];
#pragma unroll
    for (int j = 0; j < 10; ++j) {
      float4 v = *reinterpret_cast<const float4*>(&s_ip[k0 * SD + j * 4]);
      buf[4 * j + 0] = v.x; buf[4 * j + 1] = v.y;
      buf[4 * j + 2] = v.z; buf[4 * j + 3] = v.w;
      float4 u = *reinterpret_cast<const float4*>(&s_iip[k0 * SD + j * 4]);
      ibuf[4 * j + 0] = u.x; ibuf[4 * j + 1] = u.y;
      ibuf[4 * j + 2] = u.z; ibuf[4 * j + 3] = u.w;
    }
    ushort8 o;
#pragma unroll
    for (int i = 0; i < 8; ++i) {
      float d1 = 0.f, d0 = 0.f;
#pragma unroll
      for (int d = 0; d < SD; ++d) {
        float a = buf[i * SD + d] - op[d];
        float b = ibuf[i * SD + d] - iop[d];
        d1 += a * a;
        d0 += b * b;
      }
      o[i] = bf16_bits(sqrtf(d1) - sqrtf(d0));
    }
    *reinterpret_cast<ushort8*>(Wt + (size_t)n * NUM_IN + k0) = o;
  }
}

// ---------- GEMM: BK=32 dbuf (64 KB LDS -> 2 blocks/CU), lookahead KTILE ----
// 512 blocks = 256 CU x 2 co-resident, 4 waves/SIMD naturally (no forced
// launch_bounds occupancy: round 9's (512,4) caused a VGPR-64 spill disaster).
// Cross-block anti-phase overlap fills barrier/drain bubbles.
// Layout/swizzle verified zero-conflict: row-paired 128B lines, line L=row>>1,
// logical chunk c = 4*(row&1)+ck stored at c ^ (L&7).
__global__ __launch_bounds__(512, 1) void gemm_kernel(
    const ushort_t* __restrict__ A,    // [M][K] bf16
    const ushort_t* __restrict__ Bt,   // [N][K] bf16
    const float* __restrict__ bias,    // [N]
    float* __restrict__ C) {           // [M][N] f32
  __shared__ __align__(16) ushort_t sA[2 * TILEE];   // 32 KiB
  __shared__ __align__(16) ushort_t sB[2 * TILEE];   // 32 KiB

  const int tid  = threadIdx.x;
  const int w    = tid >> 6;         // 0..7
  const int l    = tid & 63;
  const int wm   = w >> 2;           // 0..1
  const int wn   = w & 3;            // 0..3
  const int lrow = l & 15;
  const int lkc  = l >> 4;           // 0..3

  // bijective XCD swizzle (512 = 8*64)
  const int orig = blockIdx.x;
  const int lin  = (orig & 7) * 64 + (orig >> 3);
  const int bx   = lin >> 4;         // 0..31 N-block
  const int by   = lin & 15;         // 0..15 M-block
  const int m0   = by * BM;
  const int n0   = bx * BN;

  // ---- fragment lane offset (elements) ----
  // phys slot = (4*(lrow&1) + lkc) ^ (lrow>>1); addr = line*64 + phys*8
  const int phys  = ((4 * (lrow & 1) + lkc) ^ (lrow >> 1));
  const int laneo = (lrow >> 1) * 64 + phys * 8;
  const int AbW = wm * 4096;   // + mh*2048 + mi*512
  const int BbW = wn * 2048;   // + nh*1024 + nj*512

  // ---- staging geometry (verified zero-conflict) ----
  const int cc  = (tid & 7) ^ ((tid >> 3) & 7);
  const int row = 2 * (tid >> 3) + (cc >> 2);
  const int ke  = (cc & 3) * 8;
  const ushort_t* pA0 = A  + (size_t)(m0 + row) * NUM_IN + ke;
  const ushort_t* pA1 = A  + (size_t)(m0 + row + 128) * NUM_IN + ke;
  const ushort_t* pB0 = Bt + (size_t)(n0 + row) * NUM_IN + ke;
  const ushort_t* pB1 = Bt + (size_t)(n0 + row + 128) * NUM_IN + ke;

#define GLDS(src, dst)                                                         \
  __builtin_amdgcn_global_load_lds(                                            \
      reinterpret_cast<const __attribute__((address_space(1))) uint32_t*>(     \
          (uintptr_t)(src)),                                                   \
      reinterpret_cast<__attribute__((address_space(3))) uint32_t*>(           \
          (uintptr_t)(dst)),                                                   \
      16, 0, 0)

// one K-tile stage = 4 gloads/thread (A:2, B:2)
#define STAGE(bs, kt)                                                          \
  {                                                                            \
    GLDS(pA0 + (kt), &sA[(bs) * TILEE + tid * 8]);                             \
    GLDS(pA1 + (kt), &sA[(bs) * TILEE + tid * 8 + 4096]);                      \
    GLDS(pB0 + (kt), &sB[(bs) * TILEE + tid * 8]);                             \
    GLDS(pB1 + (kt), &sB[(bs) * TILEE + tid * 8 + 4096]);                      \
  }

#define RD_A(arr, bs, mh)                                                      \
  {                                                                            \
    _Pragma("unroll")                                                          \
    for (int mi = 0; mi < 4; ++mi)                                             \
      arr[mi] = *reinterpret_cast<const bf16x8*>(                              \
          &sA[(bs) * TILEE + AbW + (mh) * 2048 + mi * 512 + laneo]);           \
  }
#define RD_B(arr, bs, nh)                                                      \
  {                                                                            \
    _Pragma("unroll")                                                          \
    for (int nj = 0; nj < 2; ++nj)                                             \
      arr[nj] = *reinterpret_cast<const bf16x8*>(                              \
          &sB[(bs) * TILEE + BbW + (nh) * 1024 + nj * 512 + laneo]);           \
  }

#define MFMA8(mh, nh, Aa, Bx)                                                  \
  {                                                                            \
    __builtin_amdgcn_s_setprio(1);                                             \
    _Pragma("unroll")                                                          \
    for (int mi = 0; mi < 4; ++mi)                                             \
      _Pragma("unroll")                                                        \
      for (int nj = 0; nj < 2; ++nj)                                           \
        acc[(mh) * 4 + mi][(nh) * 2 + nj] =                                    \
            __builtin_amdgcn_mfma_f32_16x16x32_bf16(                           \
                Aa[mi], Bx[nj], acc[(mh) * 4 + mi][(nh) * 2 + nj], 0, 0, 0);   \
    __builtin_amdgcn_s_setprio(0);                                             \
  }

#define LGKM(n)  asm volatile("s_waitcnt lgkmcnt(" #n ")" ::: "memory")
#define SCHED0   __builtin_amdgcn_sched_barrier(0)
#define BARRIER  __builtin_amdgcn_s_barrier()
#define VMCNT0   asm volatile("s_waitcnt vmcnt(0)" ::: "memory")

// One K-tile: read buf CUR, stage tile(ktn) -> buf NXT.
// vmcnt(0) at tile end drains this tile's 4 stage-loads (issued at tile
// start, ~a full tile of latency cover). Counted-lgkm read lookahead.
#define KTILE(CUR, NXT, ktn)                                                   \
  {                                                                            \
    STAGE(NXT, ktn)                                                            \
    RD_A(aE, CUR, 0) RD_B(b0, CUR, 0)                                          \
    RD_B(b1, CUR, 1)                                                           \
    LGKM(2); SCHED0;                                                           \
    MFMA8(0, 0, aE, b0)                                                        \
    RD_A(aO, CUR, 1)                                                           \
    LGKM(4); SCHED0;                                                           \
    MFMA8(0, 1, aE, b1)                                                        \
    LGKM(0); SCHED0;                                                           \
    MFMA8(1, 0, aO, b0)                                                        \
    MFMA8(1, 1, aO, b1)                                                        \
    VMCNT0;                                                                    \
    BARRIER;                                                                   \
  }

  f32x4 acc[8][4];
#pragma unroll
  for (int i = 0; i < 8; ++i)
#pragma unroll
    for (int j = 0; j < 4; ++j) acc[i][j] = f32x4{0.f, 0.f, 0.f, 0.f};

  bf16x8 aE[4], aO[4], b0[2], b1[2];

  // prologue: stage tile 0 into buf0
  STAGE(0, 0)
  VMCNT0;
  BARRIER;

#pragma unroll 1
  for (int tt = 0; tt < NT; tt += 2) {
    const int k1 = (tt + 1 < NT ? tt + 1 : NT - 1) * BK;
    const int k2 = (tt + 2 < NT ? tt + 2 : NT - 1) * BK;
    KTILE(0, 1, k1)
    KTILE(1, 0, k2)
  }

  // ---- epilogue: C = acc + bias ----
  const int er = l >> 4;          // 0..3
  const int ec = l & 15;
#pragma unroll
  for (int nh = 0; nh < 2; ++nh) {
#pragma unroll
    for (int nj = 0; nj < 2; ++nj) {
      const int col = n0 + wn * 64 + nh * 32 + nj * 16 + ec;
      const float bi = bias[col];
#pragma unroll
      for (int mh = 0; mh < 2; ++mh) {
#pragma unroll
        for (int mi = 0; mi < 4; ++mi) {
#pragma unroll
          for (int j = 0; j < 4; ++j) {
            const int row = m0 + wm * 128 + mh * 64 + mi * 16 + er * 4 + j;
            C[(size_t)row * NUM_OUT + col] =
                acc[mh * 4 + mi][nh * 2 + nj][j] + bi;
          }
        }
      }
    }
  }
#undef KTILE
#undef STAGE
#undef RD_A
#undef RD_B
#undef MFMA8
#undef GLDS
}

extern "C" void kernel_launch(void* const* d_in, const int* in_sizes, int n_in,
                              void* d_out, int out_size, void* d_ws, size_t ws_size,
                              hipStream_t stream) {
  const float* inputs   = (const float*)d_in[0];  // [4096,2048]
  const float* init_in  = (const float*)d_in[1];  // [2048,1,5]
  const float* init_out = (const float*)d_in[2];  // [1,8192,5]
  const float* in_pos   = (const float*)d_in[3];  // [2048,1,5]
  const float* out_pos  = (const float*)d_in[4];  // [1,8192,5]
  const float* biases   = (const float*)d_in[5];  // [8192]
  float* out = (float*)d_out;                     // [4096,8192]

  ushort_t* Abf = (ushort_t*)d_ws;
  ushort_t* Wt  = (ushort_t*)((char*)d_ws + (size_t)BATCH * NUM_IN * 2);

  cvt_kernel<<<(BATCH * NUM_IN) / (256 * 8), 256, 0, stream>>>(inputs, Abf);
  genw_kernel<<<NUM_OUT / 16, 256, 0, stream>>>(
      in_pos, out_pos, init_in, init_out, Wt);
  gemm_kernel<<<(BATCH / BM) * (NUM_OUT / BN), 512, 0, stream>>>(
      Abf, Wt, biases, out);
}

// Round 11
// 166.247 us; speedup vs baseline: 8.4985x; 1.0526x over previous
//
#include <hip/hip_runtime.h>
#include <hip/hip_bf16.h>
#include <stdint.h>

#define NUM_IN  2048   // K
#define NUM_OUT 8192   // N
#define BATCH   4096   // M
#define SD      5

#define BM 256
#define BN 256
#define BK 32
#define NT (NUM_IN / BK)      // 64 K-tiles
#define TILEE (BM * BK)       // 8192 elements per operand per K-tile

typedef __bf16 bf16x8 __attribute__((ext_vector_type(8)));
typedef float  f32x4  __attribute__((ext_vector_type(4)));
typedef unsigned short ushort_t;
typedef ushort_t ushort8 __attribute__((ext_vector_type(8)));

static __device__ __forceinline__ ushort_t bf16_bits(float f) {
  __hip_bfloat16 h = __float2bfloat16(f);
  ushort_t u;
  __builtin_memcpy(&u, &h, 2);
  return u;
}

// ---------- inputs f32 -> bf16 (vectorized) ----------
__global__ __launch_bounds__(256) void cvt_kernel(const float* __restrict__ x,
                                                  ushort_t* __restrict__ y) {
  const int i = (blockIdx.x * 256 + threadIdx.x) * 8;
  float4 v0 = *reinterpret_cast<const float4*>(x + i);
  float4 v1 = *reinterpret_cast<const float4*>(x + i + 4);
  ushort8 o;
  o[0] = bf16_bits(v0.x); o[1] = bf16_bits(v0.y);
  o[2] = bf16_bits(v0.z); o[3] = bf16_bits(v0.w);
  o[4] = bf16_bits(v1.x); o[5] = bf16_bits(v1.y);
  o[6] = bf16_bits(v1.z); o[7] = bf16_bits(v1.w);
  *reinterpret_cast<ushort8*>(y + i) = o;
}

// ---------- W^T generation: in_pos/init_in staged in LDS ----------
__global__ __launch_bounds__(256) void genw_kernel(
    const float* __restrict__ in_pos, const float* __restrict__ out_pos,
    const float* __restrict__ init_in, const float* __restrict__ init_out,
    ushort_t* __restrict__ Wt) {
  __shared__ float s_ip[NUM_IN * SD];    // 40 KB
  __shared__ float s_iip[NUM_IN * SD];   // 40 KB
  const int tid = threadIdx.x;
#pragma unroll
  for (int i = 0; i < 10; ++i) {
    const int idx = i * 1024 + tid * 4;
    *reinterpret_cast<float4*>(&s_ip[idx]) =
        *reinterpret_cast<const float4*>(in_pos + idx);
    *reinterpret_cast<float4*>(&s_iip[idx]) =
        *reinterpret_cast<const float4*>(init_in + idx);
  }
  __syncthreads();

  const int n  = blockIdx.x * 16 + (tid >> 4);
  const int kg = tid & 15;
  float op[SD], iop[SD];
#pragma unroll
  for (int d = 0; d < SD; ++d) {
    op[d]  = out_pos[n * SD + d];
    iop[d] = init_out[n * SD + d];
  }
#pragma unroll 1
  for (int kb = 0; kb < 16; ++kb) {
    const int k0 = kb * 128 + kg * 8;
    float buf[40], ibuf[40];
#pragma unroll
    for (int j = 0; j < 10; ++j) {
      float4 v = *reinterpret_cast<const float4*>(&s_ip[k0 * SD + j * 4]);
      buf[4 * j + 0] = v.x; buf[4 * j + 1] = v.y;
      buf[4 * j + 2] = v.z; buf[4 * j + 3] = v.w;
      float4 u = *reinterpret_cast<const float4*>(&s_iip[k0 * SD + j * 4]);
      ibuf[4 * j + 0] = u.x; ibuf[4 * j + 1] = u.y;
      ibuf[4 * j + 2] = u.z; ibuf[4 * j + 3] = u.w;
    }
    ushort8 o;
#pragma unroll
    for (int i = 0; i < 8; ++i) {
      float d1 = 0.f, d0 = 0.f;
#pragma unroll
      for (int d = 0; d < SD; ++d) {
        float a = buf[i * SD + d] - op[d];
        float b = ibuf[i * SD + d] - iop[d];
        d1 += a * a;
        d0 += b * b;
      }
      o[i] = bf16_bits(sqrtf(d1) - sqrtf(d0));
    }
    *reinterpret_cast<ushort8*>(Wt + (size_t)n * NUM_IN + k0) = o;
  }
}

// ---------- GEMM: ring-4 BK=32, lead-2, cross-tile read prefetch ----------
// Per K-tile: ONE barrier, ONE counted vmcnt(4) (never drains).
// After vmcnt(4)+barrier publishes buf[t+1], tile t+1's big read set
// (aE', b0') is issued UNDER tile t's last MFMA cluster, into the dead
// aE/b0 registers. b1' issues at t+1 entry. Every read burst hides under
// an 8-MFMA cluster. lgkm FIFO ledger: entry outstanding=6; LGKM(2)->
// {aE,b0}, LGKM(4)->{b1}, LGKM(0)->{aO}.
// Layout/swizzle verified zero-conflict (rounds 8/10): row-paired 128B
// lines, line L=row>>1, logical chunk c=4*(row&1)+ck stored at c^(L&7).
__global__ __launch_bounds__(512, 1) void gemm_kernel(
    const ushort_t* __restrict__ A,    // [M][K] bf16
    const ushort_t* __restrict__ Bt,   // [N][K] bf16
    const float* __restrict__ bias,    // [N]
    float* __restrict__ C) {           // [M][N] f32
  __shared__ __align__(16) ushort_t sA[4 * TILEE];   // 64 KiB
  __shared__ __align__(16) ushort_t sB[4 * TILEE];   // 64 KiB

  const int tid  = threadIdx.x;
  const int w    = tid >> 6;         // 0..7
  const int l    = tid & 63;
  const int wm   = w >> 2;           // 0..1
  const int wn   = w & 3;            // 0..3
  const int lrow = l & 15;
  const int lkc  = l >> 4;           // 0..3

  // bijective XCD swizzle (512 = 8*64)
  const int orig = blockIdx.x;
  const int lin  = (orig & 7) * 64 + (orig >> 3);
  const int bx   = lin >> 4;         // 0..31 N-block
  const int by   = lin & 15;         // 0..15 M-block
  const int m0   = by * BM;
  const int n0   = bx * BN;

  // ---- fragment lane offset (elements) ----
  const int phys  = ((4 * (lrow & 1) + lkc) ^ (lrow >> 1));
  const int laneo = (lrow >> 1) * 64 + phys * 8;
  const int AbW = wm * 4096;   // + mh*2048 + mi*512
  const int BbW = wn * 2048;   // + nh*1024 + nj*512

  // ---- staging geometry (verified zero-conflict) ----
  const int cc  = (tid & 7) ^ ((tid >> 3) & 7);
  const int row = 2 * (tid >> 3) + (cc >> 2);
  const int ke  = (cc & 3) * 8;
  const ushort_t* pA0 = A  + (size_t)(m0 + row) * NUM_IN + ke;
  const ushort_t* pA1 = A  + (size_t)(m0 + row + 128) * NUM_IN + ke;
  const ushort_t* pB0 = Bt + (size_t)(n0 + row) * NUM_IN + ke;
  const ushort_t* pB1 = Bt + (size_t)(n0 + row + 128) * NUM_IN + ke;

#define GLDS(src, dst)                                                         \
  __builtin_amdgcn_global_load_lds(                                            \
      reinterpret_cast<const __attribute__((address_space(1))) uint32_t*>(     \
          (uintptr_t)(src)),                                                   \
      reinterpret_cast<__attribute__((address_space(3))) uint32_t*>(           \
          (uintptr_t)(dst)),                                                   \
      16, 0, 0)

// one K-tile stage = 4 gloads/thread (A:2, B:2)
#define STAGE(bs, kt)                                                          \
  {                                                                            \
    GLDS(pA0 + (kt), &sA[(bs) * TILEE + tid * 8]);                             \
    GLDS(pA1 + (kt), &sA[(bs) * TILEE + tid * 8 + 4096]);                      \
    GLDS(pB0 + (kt), &sB[(bs) * TILEE + tid * 8]);                             \
    GLDS(pB1 + (kt), &sB[(bs) * TILEE + tid * 8 + 4096]);                      \
  }

#define RD_A(arr, bs, mh)                                                      \
  {                                                                            \
    _Pragma("unroll")                                                          \
    for (int mi = 0; mi < 4; ++mi)                                             \
      arr[mi] = *reinterpret_cast<const bf16x8*>(                              \
          &sA[(bs) * TILEE + AbW + (mh) * 2048 + mi * 512 + laneo]);           \
  }
#define RD_B(arr, bs, nh)                                                      \
  {                                                                            \
    _Pragma("unroll")                                                          \
    for (int nj = 0; nj < 2; ++nj)                                             \
      arr[nj] = *reinterpret_cast<const bf16x8*>(                              \
          &sB[(bs) * TILEE + BbW + (nh) * 1024 + nj * 512 + laneo]);           \
  }

#define MFMA8(mh, nh, Aa, Bx)                                                  \
  {                                                                            \
    __builtin_amdgcn_s_setprio(1);                                             \
    _Pragma("unroll")                                                          \
    for (int mi = 0; mi < 4; ++mi)                                             \
      _Pragma("unroll")                                                        \
      for (int nj = 0; nj < 2; ++nj)                                           \
        acc[(mh) * 4 + mi][(nh) * 2 + nj] =                                    \
            __builtin_amdgcn_mfma_f32_16x16x32_bf16(                           \
                Aa[mi], Bx[nj], acc[(mh) * 4 + mi][(nh) * 2 + nj], 0, 0, 0);   \
    __builtin_amdgcn_s_setprio(0);                                             \
  }

#define LGKM(n)  asm volatile("s_waitcnt lgkmcnt(" #n ")" ::: "memory")
#define SCHED0   __builtin_amdgcn_sched_barrier(0)
#define BARRIER  __builtin_amdgcn_s_barrier()
#define VMCNT4   asm volatile("s_waitcnt vmcnt(4)" ::: "memory")

// Tile t: CUR = t&3, NX1 = (t+1)&3 (read-prefetch target buffer),
// NX2 = (t+2)&3 (stage target), kt2 = clamped k-offset of tile t+2.
// Entry state: aE,b0 (tile t, from buf CUR) in flight (6 lgkm outstanding);
// buf[CUR] fully published; t+1 stage loads in flight (4 vm outstanding).
#define KTILE(CUR, NX1, NX2, kt2)                                              \
  {                                                                            \
    RD_B(b1, CUR, 1)               /* +2 -> 8 outstanding */                   \
    LGKM(2); SCHED0;               /* aE,b0 done */                            \
    MFMA8(0, 0, aE, b0)                                                        \
    RD_A(aO, CUR, 1)               /* +4 -> 6 */                               \
    LGKM(4); SCHED0;               /* b1 done */                               \
    MFMA8(0, 1, aE, b1)                                                        \
    LGKM(0); SCHED0;               /* aO done */                               \
    MFMA8(1, 0, aO, b0)                                                        \
    STAGE(NX2, kt2)                /* vm: 4 -> 8 */                            \
    VMCNT4;                        /* t+1 stage loads landed (issued t-1) */   \
    BARRIER;                       /* buf[NX1] published to all waves */       \
    RD_A(aE, NX1, 0) RD_B(b0, NX1, 0)  /* t+1 prefetch under M11; -> 6 */      \
    MFMA8(1, 1, aO, b1)                                                        \
  }

  f32x4 acc[8][4];
#pragma unroll
  for (int i = 0; i < 8; ++i)
#pragma unroll
    for (int j = 0; j < 4; ++j) acc[i][j] = f32x4{0.f, 0.f, 0.f, 0.f};

  bf16x8 aE[4], aO[4], b0[2], b1[2];

  // prologue: stage tiles 0,1; wait tile 0 (tile 1's 4 loads keep flying);
  // prime tile-0 read prefetch (aE,b0) -> 6 lgkm outstanding at loop entry.
  STAGE(0, 0)
  STAGE(1, BK)
  VMCNT4;
  BARRIER;
  RD_A(aE, 0, 0) RD_B(b0, 0, 0)

#pragma unroll 1
  for (int tt = 0; tt < NT; tt += 4) {
    const int k2 = (tt + 2 < NT ? tt + 2 : NT - 1) * BK;
    const int k3 = (tt + 3 < NT ? tt + 3 : NT - 1) * BK;
    const int k4 = (tt + 4 < NT ? tt + 4 : NT - 1) * BK;
    const int k5 = (tt + 5 < NT ? tt + 5 : NT - 1) * BK;
    KTILE(0, 1, 2, k2)
    KTILE(1, 2, 3, k3)
    KTILE(2, 3, 0, k4)
    KTILE(3, 0, 1, k5)
  }
  // loop exits with 6 dangling lgkm reads (harmless; drained below)
  asm volatile("s_waitcnt lgkmcnt(0)" ::: "memory");

  // ---- epilogue: C = acc + bias ----
  const int er = l >> 4;          // 0..3
  const int ec = l & 15;
#pragma unroll
  for (int nh = 0; nh < 2; ++nh) {
#pragma unroll
    for (int nj = 0; nj < 2; ++nj) {
      const int col = n0 + wn * 64 + nh * 32 + nj * 16 + ec;
      const float bi = bias[col];
#pragma unroll
      for (int mh = 0; mh < 2; ++mh) {
#pragma unroll
        for (int mi = 0; mi < 4; ++mi) {
#pragma unroll
          for (int j = 0; j < 4; ++j) {
            const int row = m0 + wm * 128 + mh * 64 + mi * 16 + er * 4 + j;
            C[(size_t)row * NUM_OUT + col] =
                acc[mh * 4 + mi][nh * 2 + nj][j] + bi;
          }
        }
      }
    }
  }
#undef KTILE
#undef STAGE
#undef RD_A
#undef RD_B
#undef MFMA8
#undef GLDS
}

extern "C" void kernel_launch(void* const* d_in, const int* in_sizes, int n_in,
                              void* d_out, int out_size, void* d_ws, size_t ws_size,
                              hipStream_t stream) {
  const float* inputs   = (const float*)d_in[0];  // [4096,2048]
  const float* init_in  = (const float*)d_in[1];  // [2048,1,5]
  const float* init_out = (const float*)d_in[2];  // [1,8192,5]
  const float* in_pos   = (const float*)d_in[3];  // [2048,1,5]
  const float* out_pos  = (const float*)d_in[4];  // [1,8192,5]
  const float* biases   = (const float*)d_in[5];  // [8192]
  float* out = (float*)d_out;                     // [4096,8192]

  ushort_t* Abf = (ushort_t*)d_ws;
  ushort_t* Wt  = (ushort_t*)((char*)d_ws + (size_t)BATCH * NUM_IN * 2);

  cvt_kernel<<<(BATCH * NUM_IN) / (256 * 8), 256, 0, stream>>>(inputs, Abf);
  genw_kernel<<<NUM_OUT / 16, 256, 0, stream>>>(
      in_pos, out_pos, init_in, init_out, Wt);
  gemm_kernel<<<(BATCH / BM) * (NUM_OUT / BN), 512, 0, stream>>>(
      Abf, Wt, biases, out);
}